// Round 7
// baseline (1265.592 us; speedup 1.0000x reference)
//
#include <hip/hip_runtime.h>
#include <hip/hip_bf16.h>

#define NPTS 30000
#define CH 96
#define KOFF 81
#define NB 8
#define HID 24
#define EPSV 1e-5f
#define NTILE 469            // ceil(30000/64)
#define RT 3                 // row tiles (of 64) per conv block
#define RSPLIT 157           // ceil(469/3)
#define KSPLIT 8             // k slices: 7x10 + 1x11

typedef __attribute__((ext_vector_type(8))) short bf16x8;
typedef __attribute__((ext_vector_type(4))) float f32x4;

__device__ __forceinline__ ushort f2bf(float f) {
    union { float f; unsigned int u; } x; x.f = f;
    unsigned int u = x.u;
    unsigned int r = (u + 0x7fffu + ((u >> 16) & 1u)) >> 16;
    return (ushort)r;
}

__device__ __forceinline__ void gll16(const void* g, void* l) {
    __builtin_amdgcn_global_load_lds(
        (const __attribute__((address_space(1))) unsigned int*)g,
        (__attribute__((address_space(3))) unsigned int*)l, 16, 0, 0);
}

// compute BN scale/shift into LDS (all blocks redundantly; cheap)
__device__ __forceinline__ void bn_coeffs(const float* __restrict__ ssum,
                                          const float* __restrict__ ssq,
                                          const float* __restrict__ g,
                                          const float* __restrict__ b,
                                          float* s_scale, float* s_shift) {
    int t = threadIdx.x;
    if (t < 96) {
        float mean = ssum[t] * (1.0f / NPTS);
        float var = ssq[t] * (1.0f / NPTS) - mean * mean;
        float sc = g[t] * rsqrtf(var + EPSV);
        s_scale[t] = sc;
        s_shift[t] = b[t] - mean * sc;
    }
    __syncthreads();
}

// ---------------- fused prep kernel ----------------
// blocks [0,2813): feats f32 -> bf16, zero outbuf
// blocks [2813,3282): nbr[n][k] -> nbrT[k][n]
// blocks [3282,3444): W[k][c][d] -> chunk-major wt[k][q][d][j] (bf16)
__global__ __launch_bounds__(256) void k_prep(const float* __restrict__ feats,
                                              const float* __restrict__ W1,
                                              const float* __restrict__ W2,
                                              const int* __restrict__ nbr,
                                              ushort* __restrict__ featsbf,
                                              float* __restrict__ outbuf,
                                              int* __restrict__ nbrT,
                                              ushort* __restrict__ wt1,
                                              ushort* __restrict__ wt2) {
    __shared__ __align__(16) char smem[36864];
    int bid = blockIdx.x, tid = threadIdx.x;
    if (bid < 2813) {
        int t = bid * 256 + tid;
        if (t < 720000) {
            float4 v = reinterpret_cast<const float4*>(feats)[t];
            ushort4 o;
            o.x = f2bf(v.x); o.y = f2bf(v.y); o.z = f2bf(v.z); o.w = f2bf(v.w);
            reinterpret_cast<ushort4*>(featsbf)[t] = o;
            float4 z = {0.f, 0.f, 0.f, 0.f};
            reinterpret_cast<float4*>(outbuf)[t] = z;
        }
    } else if (bid < 3282) {
        int* lds = (int*)smem;
        int n0 = (bid - 2813) * 64;
        int rows = min(64, NPTS - n0);
        int cnt = rows * 81;
        for (int i = tid; i < cnt; i += 256) lds[i] = nbr[n0 * 81 + i];
        __syncthreads();
        for (int o = tid; o < cnt; o += 256) {
            int kk = o / rows, r = o - kk * rows;
            nbrT[kk * NPTS + n0 + r] = lds[r * 81 + kk];
        }
    } else {
        float* lds = (float*)smem;
        int b = bid - 3282;
        int k = (b < 81) ? b : b - 81;
        const float* src = ((b < 81) ? W1 : W2) + k * 9216;
        ushort* dst = ((b < 81) ? wt1 : wt2) + k * 9216;
        for (int j = tid; j < 9216; j += 256) lds[j] = src[j];  // lds[c*96+d]
        __syncthreads();
        for (int o = tid; o < 9216; o += 256) {
            int q = o / 768, rem = o - q * 768, d = rem >> 3, j = rem & 7;
            dst[o] = f2bf(lds[(q * 8 + j) * 96 + d]);
        }
    }
}

// ---------------- conv: k-major, reg-hoisted B, direct-global A ----------------
// xbf: [NPTS][96] bf16; wt: [81][12][96][8] chunk-major; nbrT: [81][NPTS]
// out: [NPTS][96] f32 accumulated atomically (pre-zeroed)
__global__ __launch_bounds__(256, 4) void k_conv(const ushort* __restrict__ xbf,
                                                 const ushort* __restrict__ wt,
                                                 const int* __restrict__ nbrT,
                                                 float* __restrict__ out) {
    __shared__ __align__(16) ushort Wsm[2][9216];   // 2 x 18 KiB double buffer

    const int tid = threadIdx.x;
    const int slice = blockIdx.x / RSPLIT;
    const int rb = blockIdx.x % RSPLIT;
    const int k0 = slice * 10;
    const int k1 = k0 + ((slice == 7) ? 11 : 10);
    const int wave = tid >> 6, lane = tid & 63;
    const int r16 = lane & 15, kg = lane >> 4;
    const int tile0 = rb * RT;

    int nrow[RT];
#pragma unroll
    for (int rt = 0; rt < RT; ++rt) {
        int n = (tile0 + rt) * 64 + wave * 16 + r16;
        nrow[rt] = (n < NPTS) ? n : (NPTS - 1);   // clamp for safe loads; stores guarded
    }

    f32x4 zero4 = {0.f, 0.f, 0.f, 0.f};
    f32x4 acc[RT][6];
#pragma unroll
    for (int rt = 0; rt < RT; ++rt)
#pragma unroll
        for (int db = 0; db < 6; ++db) acc[rt][db] = zero4;

    // prologue: stage W[k0] into buf0; prefetch idx[k0]
    {
        const ushort* wsrc = wt + k0 * 9216 + lane * 8;
#pragma unroll
        for (int t = 0; t < 5; ++t) {
            int i = wave + t * 4;
            if (i < 18) gll16(wsrc + i * 512, Wsm[0] + i * 512);
        }
    }
    int idx[RT];
#pragma unroll
    for (int rt = 0; rt < RT; ++rt) idx[rt] = nbrT[k0 * NPTS + nrow[rt]];
    __syncthreads();   // compiler drains vmcnt before barrier

    int cur = 0;
    for (int k = k0; k < k1; ++k) {
        // A fragments first: direct global gather (16B per lane; longest latency)
        bf16x8 afrag[RT][3];
#pragma unroll
        for (int rt = 0; rt < RT; ++rt) {
            const ushort* as = xbf + idx[rt] * 96 + kg * 8;
#pragma unroll
            for (int c = 0; c < 3; ++c)
                afrag[rt][c] = *reinterpret_cast<const bf16x8*>(as + c * 32);
        }
        // B fragments for this k -> 72 VGPRs (reused across RT row tiles)
        bf16x8 bfrag[18];
#pragma unroll
        for (int c = 0; c < 3; ++c) {
            int q = c * 4 + kg;
#pragma unroll
            for (int db = 0; db < 6; ++db)
                bfrag[c * 6 + db] = *reinterpret_cast<const bf16x8*>(
                    &Wsm[cur][q * 768 + (db * 16 + r16) * 8]);
        }
        // stage W[k+1] into other buffer; prefetch idx[k+1]
        if (k + 1 < k1) {
            const ushort* wsrc = wt + (k + 1) * 9216 + lane * 8;
#pragma unroll
            for (int t = 0; t < 5; ++t) {
                int i = wave + t * 4;
                if (i < 18) gll16(wsrc + i * 512, Wsm[cur ^ 1] + i * 512);
            }
#pragma unroll
            for (int rt = 0; rt < RT; ++rt) idx[rt] = nbrT[(k + 1) * NPTS + nrow[rt]];
        }
        // MFMA: 54 per wave per k
#pragma unroll
        for (int rt = 0; rt < RT; ++rt)
#pragma unroll
            for (int c = 0; c < 3; ++c)
#pragma unroll
                for (int db = 0; db < 6; ++db)
                    acc[rt][db] = __builtin_amdgcn_mfma_f32_16x16x32_bf16(
                        afrag[rt][c], bfrag[c * 6 + db], acc[rt][db], 0, 0, 0);
        __syncthreads();   // drains W[k+1] staging; swap buffers
        cur ^= 1;
    }

    // epilogue: atomic accumulate
#pragma unroll
    for (int rt = 0; rt < RT; ++rt) {
        int rbase = (tile0 + rt) * 64 + wave * 16 + kg * 4;
#pragma unroll
        for (int db = 0; db < 6; ++db) {
            int col = db * 16 + r16;
#pragma unroll
            for (int i = 0; i < 4; ++i) {
                int r = rbase + i;   // C/D: row=(lane>>4)*4+i, col=lane&15
                if (r < NPTS) atomicAdd(&out[r * 96 + col], acc[rt][db][i]);
            }
        }
    }
}

// ---------------- BN stats (register-accumulated); SEG adds per-batch sums ----------------
__device__ __forceinline__ int lowb(const int* __restrict__ bids, int v) {
    int lo = 0, hi = NPTS;
    while (lo < hi) { int m = (lo + hi) >> 1; if (bids[m] < v) lo = m + 1; else hi = m; }
    return lo;
}

template <bool SEG>
__global__ __launch_bounds__(256) void k_stats(const float* __restrict__ y,
                                               const int* __restrict__ bids,
                                               float* __restrict__ ssum,
                                               float* __restrict__ ssq,
                                               float* __restrict__ segsum,
                                               float* __restrict__ cntf) {
    __shared__ float ls[96], lq[96], lg[96];
    int tid = threadIdx.x;
    if (tid < 96) { ls[tid] = 0.f; lq[tid] = 0.f; lg[tid] = 0.f; }
    __syncthreads();

    int b = 0, j, s, e;
    if (SEG) {
        b = blockIdx.x >> 5; j = blockIdx.x & 31;
        s = lowb(bids, b); e = lowb(bids, b + 1);
    } else {
        j = blockIdx.x; s = 0; e = NPTS;
    }
    const int stride = SEG ? (32 * 256) : (256 * 256);
    const int total = (e - s) * 24;           // float4 chunks in range
    const int base4 = s * 24;
    const int c40 = j * 256 + tid;

    f32x4 z = {0.f, 0.f, 0.f, 0.f};
    f32x4 sm[3] = {z, z, z}, sq[3] = {z, z, z};
    for (int c4 = c40; c4 < total; c4 += 3 * stride) {
#pragma unroll
        for (int m = 0; m < 3; ++m) {
            int c = c4 + m * stride;
            if (c < total) {
                f32x4 v = reinterpret_cast<const f32x4*>(y)[base4 + c];
                sm[m] += v; sq[m] += v * v;
            }
        }
    }
#pragma unroll
    for (int m = 0; m < 3; ++m) {
        int d0 = ((c40 + m * stride) * 4) % 96;
#pragma unroll
        for (int w = 0; w < 4; ++w) {
            atomicAdd(&ls[d0 + w], sm[m][w]);
            atomicAdd(&lq[d0 + w], sq[m][w]);
            if (SEG) atomicAdd(&lg[d0 + w], sm[m][w]);
        }
    }
    __syncthreads();
    if (tid < 96) {
        atomicAdd(&ssum[tid], ls[tid]);
        atomicAdd(&ssq[tid], lq[tid]);
        if (SEG) atomicAdd(&segsum[b * 96 + tid], lg[tid]);
    }
    if (SEG && tid == 0 && (blockIdx.x & 31) == 0) cntf[b] = (float)(e - s);
}

// bn1 + relu -> bf16; also re-zero outbuf for conv2 accumulation
__global__ void k_apply1(float* __restrict__ x,
                         const float* __restrict__ ssum, const float* __restrict__ ssq,
                         const float* __restrict__ g, const float* __restrict__ b,
                         ushort* __restrict__ h) {
    __shared__ float scale[96], shift[96];
    bn_coeffs(ssum, ssq, g, b, scale, shift);
    int t = blockIdx.x * 256 + threadIdx.x;
    if (t >= 720000) return;
    float4 v = reinterpret_cast<const float4*>(x)[t];
    int d0 = (t * 4) % 96;
    ushort4 o;
    o.x = f2bf(fmaxf(v.x * scale[d0] + shift[d0], 0.f));
    o.y = f2bf(fmaxf(v.y * scale[d0 + 1] + shift[d0 + 1], 0.f));
    o.z = f2bf(fmaxf(v.z * scale[d0 + 2] + shift[d0 + 2], 0.f));
    o.w = f2bf(fmaxf(v.w * scale[d0 + 3] + shift[d0 + 3], 0.f));
    reinterpret_cast<ushort4*>(h)[t] = o;
    float4 z = {0.f, 0.f, 0.f, 0.f};
    reinterpret_cast<float4*>(x)[t] = z;
}

// SE MLP from raw segment sums: pooled = seg/cnt * scale2 + shift2
__global__ void k_se(const float* __restrict__ segsum, const float* __restrict__ cnt,
                     const float* __restrict__ ssum, const float* __restrict__ ssq,
                     const float* __restrict__ g, const float* __restrict__ b,
                     const float* __restrict__ fc1w, const float* __restrict__ fc1b,
                     const float* __restrict__ fc2w, const float* __restrict__ fc2b,
                     float* __restrict__ sew) {
    __shared__ float scale[96], shift[96];
    __shared__ float pooled[NB][96];
    __shared__ float hid[NB][HID];
    bn_coeffs(ssum, ssq, g, b, scale, shift);
    int t = threadIdx.x;
    for (int i = t; i < NB * 96; i += 256) {
        int bb = i / 96, d = i - bb * 96;
        pooled[bb][d] = segsum[i] / fmaxf(cnt[bb], 1.f) * scale[d] + shift[d];
    }
    __syncthreads();
    if (t < NB * HID) {
        int bb = t / HID, h = t - bb * HID;
        float s = fc1b[h];
        for (int d = 0; d < 96; ++d) s += pooled[bb][d] * fc1w[d * HID + h];
        hid[bb][h] = fmaxf(s, 0.f);
    }
    __syncthreads();
    for (int i = t; i < NB * 96; i += 256) {
        int bb = i / 96, d = i - bb * 96;
        float s = fc2b[d];
        for (int h = 0; h < HID; ++h) s += hid[bb][h] * fc2w[h * 96 + d];
        sew[i] = 1.f / (1.f + expf(-s));
    }
}

// final: relu( (y2*scale2+shift2) * sew[b] + feats )
__global__ void k_final(const float* __restrict__ out2, const float* __restrict__ feats,
                        const float* __restrict__ ssum, const float* __restrict__ ssq,
                        const float* __restrict__ g, const float* __restrict__ b,
                        const float* __restrict__ sew, const int* __restrict__ bids,
                        float* __restrict__ out) {
    __shared__ float scale[96], shift[96];
    bn_coeffs(ssum, ssq, g, b, scale, shift);
    int t = blockIdx.x * 256 + threadIdx.x;
    if (t >= 720000) return;
    int e0 = t * 4;
    int n = e0 / 96;
    int d0 = e0 - n * 96;
    int bb = bids[n];
    const float* w = sew + bb * 96;
    float4 v = reinterpret_cast<const float4*>(out2)[t];
    float4 f = reinterpret_cast<const float4*>(feats)[t];
    float4 o;
    o.x = fmaxf((v.x * scale[d0] + shift[d0]) * w[d0] + f.x, 0.f);
    o.y = fmaxf((v.y * scale[d0 + 1] + shift[d0 + 1]) * w[d0 + 1] + f.y, 0.f);
    o.z = fmaxf((v.z * scale[d0 + 2] + shift[d0 + 2]) * w[d0 + 2] + f.z, 0.f);
    o.w = fmaxf((v.w * scale[d0 + 3] + shift[d0 + 3]) * w[d0 + 3] + f.w, 0.f);
    reinterpret_cast<float4*>(out)[t] = o;
}

// ---------------- launch ----------------

extern "C" void kernel_launch(void* const* d_in, const int* in_sizes, int n_in,
                              void* d_out, int out_size, void* d_ws, size_t ws_size,
                              hipStream_t stream) {
    const float* feats = (const float*)d_in[0];
    const float* W1 = (const float*)d_in[1];
    const float* g1 = (const float*)d_in[2];
    const float* b1 = (const float*)d_in[3];
    const float* W2 = (const float*)d_in[4];
    const float* g2 = (const float*)d_in[5];
    const float* b2 = (const float*)d_in[6];
    const float* fc1w = (const float*)d_in[7];
    const float* fc1b = (const float*)d_in[8];
    const float* fc2w = (const float*)d_in[9];
    const float* fc2b = (const float*)d_in[10];
    const int* nbr = (const int*)d_in[11];
    const int* bids = (const int*)d_in[12];
    float* out = (float*)d_out;

    char* ws = (char*)d_ws;
    ushort* featsbf = (ushort*)(ws + 0);               // 5,760,000 B
    ushort* wt1 = (ushort*)(ws + 5760000);             // 1,492,992 B
    ushort* wt2 = (ushort*)(ws + 7252992);             // 1,492,992 B
    int* nbrT = (int*)(ws + 8745984);                  // 9,720,000 B
    float* outbuf = (float*)(ws + 18465984);           // 11,520,000 B
    ushort* h1bf = (ushort*)(ws + 29985984);           // 5,760,000 B
    float* small = (float*)(ws + 35745984);            // 16,384 B
    float* sum1 = small + 0;
    float* sq1 = small + 96;
    float* sum2 = small + 192;
    float* sq2 = small + 288;
    float* segsum = small + 768;   // [8][96]
    float* cntf = small + 1536;    // [8]
    float* sew = small + 1544;     // [8][96]

    const int gE = 2813;               // ceil(720000/256)
    const int gC = KSPLIT * RSPLIT;    // 1256

    hipMemsetAsync(small, 0, 16384, stream);
    k_prep<<<3444, 256, 0, stream>>>(feats, W1, W2, nbr, featsbf, outbuf, nbrT, wt1, wt2);

    k_conv<<<gC, 256, 0, stream>>>(featsbf, wt1, nbrT, outbuf);
    k_stats<false><<<256, 256, 0, stream>>>(outbuf, bids, sum1, sq1, segsum, cntf);
    k_apply1<<<gE, 256, 0, stream>>>(outbuf, sum1, sq1, g1, b1, h1bf);

    k_conv<<<gC, 256, 0, stream>>>(h1bf, wt2, nbrT, outbuf);
    k_stats<true><<<256, 256, 0, stream>>>(outbuf, bids, sum2, sq2, segsum, cntf);

    k_se<<<1, 256, 0, stream>>>(segsum, cntf, sum2, sq2, g2, b2, fc1w, fc1b, fc2w, fc2b, sew);
    k_final<<<gE, 256, 0, stream>>>(outbuf, feats, sum2, sq2, g2, b2, sew, bids, out);
}

// Round 8
// 382.560 us; speedup vs baseline: 3.3082x; 3.3082x over previous
//
#include <hip/hip_runtime.h>
#include <hip/hip_bf16.h>

#define NPTS 30000
#define CH 96
#define KOFF 81
#define NB 8
#define HID 24
#define EPSV 1e-5f
#define NTILE 469            // ceil(30000/64)
#define RT 3                 // row tiles (of 64) per conv block
#define RSPLIT 157           // ceil(469/3)
#define KSPLIT 8             // k slices: 7x10 + 1x11

typedef __attribute__((ext_vector_type(8))) short bf16x8;
typedef __attribute__((ext_vector_type(4))) float f32x4;

__device__ __forceinline__ ushort f2bf(float f) {
    union { float f; unsigned int u; } x; x.f = f;
    unsigned int u = x.u;
    unsigned int r = (u + 0x7fffu + ((u >> 16) & 1u)) >> 16;
    return (ushort)r;
}

__device__ __forceinline__ void gll16(const void* g, void* l) {
    __builtin_amdgcn_global_load_lds(
        (const __attribute__((address_space(1))) unsigned int*)g,
        (__attribute__((address_space(3))) unsigned int*)l, 16, 0, 0);
}

// compute BN scale/shift into LDS (all blocks redundantly; cheap)
__device__ __forceinline__ void bn_coeffs(const float* __restrict__ ssum,
                                          const float* __restrict__ ssq,
                                          const float* __restrict__ g,
                                          const float* __restrict__ b,
                                          float* s_scale, float* s_shift) {
    int t = threadIdx.x;
    if (t < 96) {
        float mean = ssum[t] * (1.0f / NPTS);
        float var = ssq[t] * (1.0f / NPTS) - mean * mean;
        float sc = g[t] * rsqrtf(var + EPSV);
        s_scale[t] = sc;
        s_shift[t] = b[t] - mean * sc;
    }
    __syncthreads();
}

// ---------------- fused prep kernel ----------------
// blocks [0,2813): feats f32 -> bf16, zero outbuf
// blocks [2813,3282): nbr[n][k] -> nbrT[k][n]
// blocks [3282,3444): W[k][c][d] -> chunk-major wt[k][q][d][j] (bf16)
__global__ __launch_bounds__(256) void k_prep(const float* __restrict__ feats,
                                              const float* __restrict__ W1,
                                              const float* __restrict__ W2,
                                              const int* __restrict__ nbr,
                                              ushort* __restrict__ featsbf,
                                              float* __restrict__ outbuf,
                                              int* __restrict__ nbrT,
                                              ushort* __restrict__ wt1,
                                              ushort* __restrict__ wt2) {
    __shared__ __align__(16) char smem[36864];
    int bid = blockIdx.x, tid = threadIdx.x;
    if (bid < 2813) {
        int t = bid * 256 + tid;
        if (t < 720000) {
            float4 v = reinterpret_cast<const float4*>(feats)[t];
            ushort4 o;
            o.x = f2bf(v.x); o.y = f2bf(v.y); o.z = f2bf(v.z); o.w = f2bf(v.w);
            reinterpret_cast<ushort4*>(featsbf)[t] = o;
            float4 z = {0.f, 0.f, 0.f, 0.f};
            reinterpret_cast<float4*>(outbuf)[t] = z;
        }
    } else if (bid < 3282) {
        int* lds = (int*)smem;
        int n0 = (bid - 2813) * 64;
        int rows = min(64, NPTS - n0);
        int cnt = rows * 81;
        for (int i = tid; i < cnt; i += 256) lds[i] = nbr[n0 * 81 + i];
        __syncthreads();
        for (int o = tid; o < cnt; o += 256) {
            int kk = o / rows, r = o - kk * rows;
            nbrT[kk * NPTS + n0 + r] = lds[r * 81 + kk];
        }
    } else {
        float* lds = (float*)smem;
        int b = bid - 3282;
        int k = (b < 81) ? b : b - 81;
        const float* src = ((b < 81) ? W1 : W2) + k * 9216;
        ushort* dst = ((b < 81) ? wt1 : wt2) + k * 9216;
        for (int j = tid; j < 9216; j += 256) lds[j] = src[j];  // lds[c*96+d]
        __syncthreads();
        for (int o = tid; o < 9216; o += 256) {
            int q = o / 768, rem = o - q * 768, d = rem >> 3, j = rem & 7;
            dst[o] = f2bf(lds[(q * 8 + j) * 96 + d]);
        }
    }
}

// ---------------- conv: k-major, per-chunk B, direct-global A ----------------
// xbf: [NPTS][96] bf16; wt: [81][12][96][8] chunk-major; nbrT: [81][NPTS]
// out: [NPTS][96] f32 accumulated atomically (pre-zeroed)
__global__ __launch_bounds__(256, 3) void k_conv(const ushort* __restrict__ xbf,
                                                 const ushort* __restrict__ wt,
                                                 const int* __restrict__ nbrT,
                                                 float* __restrict__ out) {
    __shared__ __align__(16) ushort Wsm[2][9216];   // 2 x 18 KiB double buffer

    const int tid = threadIdx.x;
    const int slice = blockIdx.x / RSPLIT;
    const int rb = blockIdx.x % RSPLIT;
    const int k0 = slice * 10;
    const int k1 = k0 + ((slice == 7) ? 11 : 10);
    const int wave = tid >> 6, lane = tid & 63;
    const int r16 = lane & 15, kg = lane >> 4;
    const int tile0 = rb * RT;

    int nrow[RT];
#pragma unroll
    for (int rt = 0; rt < RT; ++rt) {
        int n = (tile0 + rt) * 64 + wave * 16 + r16;
        nrow[rt] = (n < NPTS) ? n : (NPTS - 1);   // clamp for safe loads; stores guarded
    }

    f32x4 zero4 = {0.f, 0.f, 0.f, 0.f};
    f32x4 acc[RT][6];
#pragma unroll
    for (int rt = 0; rt < RT; ++rt)
#pragma unroll
        for (int db = 0; db < 6; ++db) acc[rt][db] = zero4;

    // prologue: stage W[k0] into buf0; prefetch idx[k0]
    {
        const ushort* wsrc = wt + k0 * 9216 + lane * 8;
#pragma unroll
        for (int t = 0; t < 5; ++t) {
            int i = wave + t * 4;
            if (i < 18) gll16(wsrc + i * 512, Wsm[0] + i * 512);
        }
    }
    int idx[RT];
#pragma unroll
    for (int rt = 0; rt < RT; ++rt) idx[rt] = nbrT[k0 * NPTS + nrow[rt]];
    __syncthreads();   // compiler drains vmcnt before barrier

    int cur = 0;
    for (int k = k0; k < k1; ++k) {
        // A fragments first: direct global gather (16B per lane; longest latency)
        bf16x8 afrag[RT][3];
#pragma unroll
        for (int rt = 0; rt < RT; ++rt) {
            const ushort* as = xbf + idx[rt] * 96 + kg * 8;
#pragma unroll
            for (int c = 0; c < 3; ++c)
                afrag[rt][c] = *reinterpret_cast<const bf16x8*>(as + c * 32);
        }
        // stage W[k+1] into other buffer; prefetch idx[k+1]
        if (k + 1 < k1) {
            const ushort* wsrc = wt + (k + 1) * 9216 + lane * 8;
#pragma unroll
            for (int t = 0; t < 5; ++t) {
                int i = wave + t * 4;
                if (i < 18) gll16(wsrc + i * 512, Wsm[cur ^ 1] + i * 512);
            }
#pragma unroll
            for (int rt = 0; rt < RT; ++rt) idx[rt] = nbrT[(k + 1) * NPTS + nrow[rt]];
        }
        // per-c B fragments (6 live regs x4 = 24) + 18 MFMAs each
#pragma unroll
        for (int c = 0; c < 3; ++c) {
            const int q = c * 4 + kg;
            bf16x8 bfrag[6];
#pragma unroll
            for (int db = 0; db < 6; ++db)
                bfrag[db] = *reinterpret_cast<const bf16x8*>(
                    &Wsm[cur][q * 768 + (db * 16 + r16) * 8]);
#pragma unroll
            for (int rt = 0; rt < RT; ++rt)
#pragma unroll
                for (int db = 0; db < 6; ++db)
                    acc[rt][db] = __builtin_amdgcn_mfma_f32_16x16x32_bf16(
                        afrag[rt][c], bfrag[db], acc[rt][db], 0, 0, 0);
        }
        __syncthreads();   // drains W[k+1] staging; swap buffers
        cur ^= 1;
    }

    // epilogue: atomic accumulate
#pragma unroll
    for (int rt = 0; rt < RT; ++rt) {
        int rbase = (tile0 + rt) * 64 + wave * 16 + kg * 4;
#pragma unroll
        for (int db = 0; db < 6; ++db) {
            int col = db * 16 + r16;
#pragma unroll
            for (int i = 0; i < 4; ++i) {
                int r = rbase + i;   // C/D: row=(lane>>4)*4+i, col=lane&15
                if (r < NPTS) atomicAdd(&out[r * 96 + col], acc[rt][db][i]);
            }
        }
    }
}

// ---------------- BN stats (register-accumulated); SEG adds per-batch sums ----------------
__device__ __forceinline__ int lowb(const int* __restrict__ bids, int v) {
    int lo = 0, hi = NPTS;
    while (lo < hi) { int m = (lo + hi) >> 1; if (bids[m] < v) lo = m + 1; else hi = m; }
    return lo;
}

template <bool SEG>
__global__ __launch_bounds__(256) void k_stats(const float* __restrict__ y,
                                               const int* __restrict__ bids,
                                               float* __restrict__ ssum,
                                               float* __restrict__ ssq,
                                               float* __restrict__ segsum,
                                               float* __restrict__ cntf) {
    __shared__ float ls[96], lq[96], lg[96];
    int tid = threadIdx.x;
    if (tid < 96) { ls[tid] = 0.f; lq[tid] = 0.f; lg[tid] = 0.f; }
    __syncthreads();

    int b = 0, j, s, e;
    if (SEG) {
        b = blockIdx.x >> 5; j = blockIdx.x & 31;
        s = lowb(bids, b); e = lowb(bids, b + 1);
    } else {
        j = blockIdx.x; s = 0; e = NPTS;
    }
    const int stride = SEG ? (32 * 256) : (256 * 256);
    const int total = (e - s) * 24;           // float4 chunks in range
    const int base4 = s * 24;
    const int c40 = j * 256 + tid;

    f32x4 z = {0.f, 0.f, 0.f, 0.f};
    f32x4 sm[3] = {z, z, z}, sq[3] = {z, z, z};
    for (int c4 = c40; c4 < total; c4 += 3 * stride) {
#pragma unroll
        for (int m = 0; m < 3; ++m) {
            int c = c4 + m * stride;
            if (c < total) {
                f32x4 v = reinterpret_cast<const f32x4*>(y)[base4 + c];
                sm[m] += v; sq[m] += v * v;
            }
        }
    }
#pragma unroll
    for (int m = 0; m < 3; ++m) {
        int d0 = ((c40 + m * stride) * 4) % 96;
#pragma unroll
        for (int w = 0; w < 4; ++w) {
            atomicAdd(&ls[d0 + w], sm[m][w]);
            atomicAdd(&lq[d0 + w], sq[m][w]);
            if (SEG) atomicAdd(&lg[d0 + w], sm[m][w]);
        }
    }
    __syncthreads();
    if (tid < 96) {
        atomicAdd(&ssum[tid], ls[tid]);
        atomicAdd(&ssq[tid], lq[tid]);
        if (SEG) atomicAdd(&segsum[b * 96 + tid], lg[tid]);
    }
    if (SEG && tid == 0 && (blockIdx.x & 31) == 0) cntf[b] = (float)(e - s);
}

// bn1 + relu -> bf16; also re-zero outbuf for conv2 accumulation
__global__ void k_apply1(float* __restrict__ x,
                         const float* __restrict__ ssum, const float* __restrict__ ssq,
                         const float* __restrict__ g, const float* __restrict__ b,
                         ushort* __restrict__ h) {
    __shared__ float scale[96], shift[96];
    bn_coeffs(ssum, ssq, g, b, scale, shift);
    int t = blockIdx.x * 256 + threadIdx.x;
    if (t >= 720000) return;
    float4 v = reinterpret_cast<const float4*>(x)[t];
    int d0 = (t * 4) % 96;
    ushort4 o;
    o.x = f2bf(fmaxf(v.x * scale[d0] + shift[d0], 0.f));
    o.y = f2bf(fmaxf(v.y * scale[d0 + 1] + shift[d0 + 1], 0.f));
    o.z = f2bf(fmaxf(v.z * scale[d0 + 2] + shift[d0 + 2], 0.f));
    o.w = f2bf(fmaxf(v.w * scale[d0 + 3] + shift[d0 + 3], 0.f));
    reinterpret_cast<ushort4*>(h)[t] = o;
    float4 z = {0.f, 0.f, 0.f, 0.f};
    reinterpret_cast<float4*>(x)[t] = z;
}

// SE MLP from raw segment sums: pooled = seg/cnt * scale2 + shift2
__global__ void k_se(const float* __restrict__ segsum, const float* __restrict__ cnt,
                     const float* __restrict__ ssum, const float* __restrict__ ssq,
                     const float* __restrict__ g, const float* __restrict__ b,
                     const float* __restrict__ fc1w, const float* __restrict__ fc1b,
                     const float* __restrict__ fc2w, const float* __restrict__ fc2b,
                     float* __restrict__ sew) {
    __shared__ float scale[96], shift[96];
    __shared__ float pooled[NB][96];
    __shared__ float hid[NB][HID];
    bn_coeffs(ssum, ssq, g, b, scale, shift);
    int t = threadIdx.x;
    for (int i = t; i < NB * 96; i += 256) {
        int bb = i / 96, d = i - bb * 96;
        pooled[bb][d] = segsum[i] / fmaxf(cnt[bb], 1.f) * scale[d] + shift[d];
    }
    __syncthreads();
    if (t < NB * HID) {
        int bb = t / HID, h = t - bb * HID;
        float s = fc1b[h];
        for (int d = 0; d < 96; ++d) s += pooled[bb][d] * fc1w[d * HID + h];
        hid[bb][h] = fmaxf(s, 0.f);
    }
    __syncthreads();
    for (int i = t; i < NB * 96; i += 256) {
        int bb = i / 96, d = i - bb * 96;
        float s = fc2b[d];
        for (int h = 0; h < HID; ++h) s += hid[bb][h] * fc2w[h * 96 + d];
        sew[i] = 1.f / (1.f + expf(-s));
    }
}

// final: relu( (y2*scale2+shift2) * sew[b] + feats )
__global__ void k_final(const float* __restrict__ out2, const float* __restrict__ feats,
                        const float* __restrict__ ssum, const float* __restrict__ ssq,
                        const float* __restrict__ g, const float* __restrict__ b,
                        const float* __restrict__ sew, const int* __restrict__ bids,
                        float* __restrict__ out) {
    __shared__ float scale[96], shift[96];
    bn_coeffs(ssum, ssq, g, b, scale, shift);
    int t = blockIdx.x * 256 + threadIdx.x;
    if (t >= 720000) return;
    int e0 = t * 4;
    int n = e0 / 96;
    int d0 = e0 - n * 96;
    int bb = bids[n];
    const float* w = sew + bb * 96;
    float4 v = reinterpret_cast<const float4*>(out2)[t];
    float4 f = reinterpret_cast<const float4*>(feats)[t];
    float4 o;
    o.x = fmaxf((v.x * scale[d0] + shift[d0]) * w[d0] + f.x, 0.f);
    o.y = fmaxf((v.y * scale[d0 + 1] + shift[d0 + 1]) * w[d0 + 1] + f.y, 0.f);
    o.z = fmaxf((v.z * scale[d0 + 2] + shift[d0 + 2]) * w[d0 + 2] + f.z, 0.f);
    o.w = fmaxf((v.w * scale[d0 + 3] + shift[d0 + 3]) * w[d0 + 3] + f.w, 0.f);
    reinterpret_cast<float4*>(out)[t] = o;
}

// ---------------- launch ----------------

extern "C" void kernel_launch(void* const* d_in, const int* in_sizes, int n_in,
                              void* d_out, int out_size, void* d_ws, size_t ws_size,
                              hipStream_t stream) {
    const float* feats = (const float*)d_in[0];
    const float* W1 = (const float*)d_in[1];
    const float* g1 = (const float*)d_in[2];
    const float* b1 = (const float*)d_in[3];
    const float* W2 = (const float*)d_in[4];
    const float* g2 = (const float*)d_in[5];
    const float* b2 = (const float*)d_in[6];
    const float* fc1w = (const float*)d_in[7];
    const float* fc1b = (const float*)d_in[8];
    const float* fc2w = (const float*)d_in[9];
    const float* fc2b = (const float*)d_in[10];
    const int* nbr = (const int*)d_in[11];
    const int* bids = (const int*)d_in[12];
    float* out = (float*)d_out;

    char* ws = (char*)d_ws;
    ushort* featsbf = (ushort*)(ws + 0);               // 5,760,000 B
    ushort* wt1 = (ushort*)(ws + 5760000);             // 1,492,992 B
    ushort* wt2 = (ushort*)(ws + 7252992);             // 1,492,992 B
    int* nbrT = (int*)(ws + 8745984);                  // 9,720,000 B
    float* outbuf = (float*)(ws + 18465984);           // 11,520,000 B
    ushort* h1bf = (ushort*)(ws + 29985984);           // 5,760,000 B
    float* small = (float*)(ws + 35745984);            // 16,384 B
    float* sum1 = small + 0;
    float* sq1 = small + 96;
    float* sum2 = small + 192;
    float* sq2 = small + 288;
    float* segsum = small + 768;   // [8][96]
    float* cntf = small + 1536;    // [8]
    float* sew = small + 1544;     // [8][96]

    const int gE = 2813;               // ceil(720000/256)
    const int gC = KSPLIT * RSPLIT;    // 1256

    hipMemsetAsync(small, 0, 16384, stream);
    k_prep<<<3444, 256, 0, stream>>>(feats, W1, W2, nbr, featsbf, outbuf, nbrT, wt1, wt2);

    k_conv<<<gC, 256, 0, stream>>>(featsbf, wt1, nbrT, outbuf);
    k_stats<false><<<256, 256, 0, stream>>>(outbuf, bids, sum1, sq1, segsum, cntf);
    k_apply1<<<gE, 256, 0, stream>>>(outbuf, sum1, sq1, g1, b1, h1bf);

    k_conv<<<gC, 256, 0, stream>>>(h1bf, wt2, nbrT, outbuf);
    k_stats<true><<<256, 256, 0, stream>>>(outbuf, bids, sum2, sq2, segsum, cntf);

    k_se<<<1, 256, 0, stream>>>(segsum, cntf, sum2, sq2, g2, b2, fc1w, fc1b, fc2w, fc2b, sew);
    k_final<<<gE, 256, 0, stream>>>(outbuf, feats, sum2, sq2, g2, b2, sew, bids, out);
}

// Round 9
// 364.599 us; speedup vs baseline: 3.4712x; 1.0493x over previous
//
#include <hip/hip_runtime.h>
#include <hip/hip_bf16.h>

#define NPTS 30000
#define CH 96
#define KOFF 81
#define NB 8
#define HID 24
#define EPSV 1e-5f
#define RT 3                 // 16-row groups per wave (48 rows)
#define GSPLIT 625           // 30000 / 48
#define KSPLIT 4             // k slices: 20,20,20,21

typedef __attribute__((ext_vector_type(8))) short bf16x8;
typedef __attribute__((ext_vector_type(4))) float f32x4;

__device__ __forceinline__ ushort f2bf(float f) {
    union { float f; unsigned int u; } x; x.f = f;
    unsigned int u = x.u;
    unsigned int r = (u + 0x7fffu + ((u >> 16) & 1u)) >> 16;
    return (ushort)r;
}

// compute BN scale/shift into LDS (all blocks redundantly; cheap)
__device__ __forceinline__ void bn_coeffs(const float* __restrict__ ssum,
                                          const float* __restrict__ ssq,
                                          const float* __restrict__ g,
                                          const float* __restrict__ b,
                                          float* s_scale, float* s_shift) {
    int t = threadIdx.x;
    if (t < 96) {
        float mean = ssum[t] * (1.0f / NPTS);
        float var = ssq[t] * (1.0f / NPTS) - mean * mean;
        float sc = g[t] * rsqrtf(var + EPSV);
        s_scale[t] = sc;
        s_shift[t] = b[t] - mean * sc;
    }
    __syncthreads();
}

// ---------------- fused prep kernel ----------------
// blocks [0,2813): feats f32 -> bf16, zero outbuf
// blocks [2813,3282): nbr[n][k] -> nbrT[k][n]
// blocks [3282,3444): W[k][c][d] -> chunk-major wt[k][q][d][j] (bf16)
__global__ __launch_bounds__(256) void k_prep(const float* __restrict__ feats,
                                              const float* __restrict__ W1,
                                              const float* __restrict__ W2,
                                              const int* __restrict__ nbr,
                                              ushort* __restrict__ featsbf,
                                              float* __restrict__ outbuf,
                                              int* __restrict__ nbrT,
                                              ushort* __restrict__ wt1,
                                              ushort* __restrict__ wt2) {
    __shared__ __align__(16) char smem[36864];
    int bid = blockIdx.x, tid = threadIdx.x;
    if (bid < 2813) {
        int t = bid * 256 + tid;
        if (t < 720000) {
            float4 v = reinterpret_cast<const float4*>(feats)[t];
            ushort4 o;
            o.x = f2bf(v.x); o.y = f2bf(v.y); o.z = f2bf(v.z); o.w = f2bf(v.w);
            reinterpret_cast<ushort4*>(featsbf)[t] = o;
            float4 z = {0.f, 0.f, 0.f, 0.f};
            reinterpret_cast<float4*>(outbuf)[t] = z;
        }
    } else if (bid < 3282) {
        int* lds = (int*)smem;
        int n0 = (bid - 2813) * 64;
        int rows = min(64, NPTS - n0);
        int cnt = rows * 81;
        for (int i = tid; i < cnt; i += 256) lds[i] = nbr[n0 * 81 + i];
        __syncthreads();
        for (int o = tid; o < cnt; o += 256) {
            int kk = o / rows, r = o - kk * rows;
            nbrT[kk * NPTS + n0 + r] = lds[r * 81 + kk];
        }
    } else {
        float* lds = (float*)smem;
        int b = bid - 3282;
        int k = (b < 81) ? b : b - 81;
        const float* src = ((b < 81) ? W1 : W2) + k * 9216;
        ushort* dst = ((b < 81) ? wt1 : wt2) + k * 9216;
        for (int j = tid; j < 9216; j += 256) lds[j] = src[j];  // lds[c*96+d]
        __syncthreads();
        for (int o = tid; o < 9216; o += 256) {
            int q = o / 768, rem = o - q * 768, d = rem >> 3, j = rem & 7;
            dst[o] = f2bf(lds[(q * 8 + j) * 96 + d]);
        }
    }
}

// ---------------- conv: wave-per-block, no LDS, no barriers ----------------
// xbf: [NPTS][96] bf16; wt: [81][12][96][8] chunk-major; nbrT: [81][NPTS]
// out: [NPTS][96] f32 accumulated atomically (pre-zeroed)
// Each 64-thread block = 1 wave owning 48 rows x one k-slice. All operands
// stream global->reg (W[k]=18KB is L1/L2-hot across ~625 same-slice waves).
__global__ __launch_bounds__(64) void k_conv(const ushort* __restrict__ xbf,
                                             const ushort* __restrict__ wt,
                                             const int* __restrict__ nbrT,
                                             float* __restrict__ out) {
    const int lane = threadIdx.x;
    const int slice = blockIdx.x / GSPLIT;
    const int g = blockIdx.x % GSPLIT;
    const int k0 = slice * 20;
    const int k1 = k0 + ((slice == 3) ? 21 : 20);
    const int r16 = lane & 15, kg = lane >> 4;
    const int row0 = g * 48;

    f32x4 zero4 = {0.f, 0.f, 0.f, 0.f};
    f32x4 acc[RT][6];
#pragma unroll
    for (int rt = 0; rt < RT; ++rt)
#pragma unroll
        for (int db = 0; db < 6; ++db) acc[rt][db] = zero4;

    int idx[RT];
#pragma unroll
    for (int rt = 0; rt < RT; ++rt) idx[rt] = nbrT[k0 * NPTS + row0 + rt * 16 + r16];

    for (int k = k0; k < k1; ++k) {
        // A fragments: direct global gather, 16B/lane, issued first
        bf16x8 afrag[RT][3];
#pragma unroll
        for (int rt = 0; rt < RT; ++rt) {
            const ushort* as = xbf + idx[rt] * 96 + kg * 8;
#pragma unroll
            for (int c = 0; c < 3; ++c)
                afrag[rt][c] = *reinterpret_cast<const bf16x8*>(as + c * 32);
        }
        // prefetch next k's neighbor indices
        if (k + 1 < k1) {
#pragma unroll
            for (int rt = 0; rt < RT; ++rt)
                idx[rt] = nbrT[(k + 1) * NPTS + row0 + rt * 16 + r16];
        }
        // B fragments per c-chunk: 16B/lane contiguous global loads (L1-hot)
        const ushort* wk = wt + k * 9216;
#pragma unroll
        for (int c = 0; c < 3; ++c) {
            const int q = c * 4 + kg;
            bf16x8 bfrag[6];
#pragma unroll
            for (int db = 0; db < 6; ++db)
                bfrag[db] = *reinterpret_cast<const bf16x8*>(
                    wk + q * 768 + (db * 16 + r16) * 8);
#pragma unroll
            for (int rt = 0; rt < RT; ++rt)
#pragma unroll
                for (int db = 0; db < 6; ++db)
                    acc[rt][db] = __builtin_amdgcn_mfma_f32_16x16x32_bf16(
                        afrag[rt][c], bfrag[db], acc[rt][db], 0, 0, 0);
        }
    }

    // epilogue: atomic accumulate (rows always < 30000: 625*48 == 30000)
#pragma unroll
    for (int rt = 0; rt < RT; ++rt) {
        int rbase = row0 + rt * 16 + kg * 4;
#pragma unroll
        for (int db = 0; db < 6; ++db) {
            int col = db * 16 + r16;
#pragma unroll
            for (int i = 0; i < 4; ++i)
                atomicAdd(&out[(rbase + i) * 96 + col], acc[rt][db][i]);
        }
    }
}

// ---------------- BN stats (register-accumulated); SEG adds per-batch sums ----------------
__device__ __forceinline__ int lowb(const int* __restrict__ bids, int v) {
    int lo = 0, hi = NPTS;
    while (lo < hi) { int m = (lo + hi) >> 1; if (bids[m] < v) lo = m + 1; else hi = m; }
    return lo;
}

template <bool SEG>
__global__ __launch_bounds__(256) void k_stats(const float* __restrict__ y,
                                               const int* __restrict__ bids,
                                               float* __restrict__ ssum,
                                               float* __restrict__ ssq,
                                               float* __restrict__ segsum,
                                               float* __restrict__ cntf) {
    __shared__ float ls[96], lq[96], lg[96];
    int tid = threadIdx.x;
    if (tid < 96) { ls[tid] = 0.f; lq[tid] = 0.f; lg[tid] = 0.f; }
    __syncthreads();

    int b = 0, j, s, e;
    if (SEG) {
        b = blockIdx.x >> 5; j = blockIdx.x & 31;
        s = lowb(bids, b); e = lowb(bids, b + 1);
    } else {
        j = blockIdx.x; s = 0; e = NPTS;
    }
    const int stride = SEG ? (32 * 256) : (256 * 256);
    const int total = (e - s) * 24;           // float4 chunks in range
    const int base4 = s * 24;
    const int c40 = j * 256 + tid;

    f32x4 z = {0.f, 0.f, 0.f, 0.f};
    f32x4 sm[3] = {z, z, z}, sq[3] = {z, z, z};
    for (int c4 = c40; c4 < total; c4 += 3 * stride) {
#pragma unroll
        for (int m = 0; m < 3; ++m) {
            int c = c4 + m * stride;
            if (c < total) {
                f32x4 v = reinterpret_cast<const f32x4*>(y)[base4 + c];
                sm[m] += v; sq[m] += v * v;
            }
        }
    }
#pragma unroll
    for (int m = 0; m < 3; ++m) {
        int d0 = ((c40 + m * stride) * 4) % 96;
#pragma unroll
        for (int w = 0; w < 4; ++w) {
            atomicAdd(&ls[d0 + w], sm[m][w]);
            atomicAdd(&lq[d0 + w], sq[m][w]);
            if (SEG) atomicAdd(&lg[d0 + w], sm[m][w]);
        }
    }
    __syncthreads();
    if (tid < 96) {
        atomicAdd(&ssum[tid], ls[tid]);
        atomicAdd(&ssq[tid], lq[tid]);
        if (SEG) atomicAdd(&segsum[b * 96 + tid], lg[tid]);
    }
    if (SEG && tid == 0 && (blockIdx.x & 31) == 0) cntf[b] = (float)(e - s);
}

// bn1 + relu -> bf16; also re-zero outbuf for conv2 accumulation
__global__ void k_apply1(float* __restrict__ x,
                         const float* __restrict__ ssum, const float* __restrict__ ssq,
                         const float* __restrict__ g, const float* __restrict__ b,
                         ushort* __restrict__ h) {
    __shared__ float scale[96], shift[96];
    bn_coeffs(ssum, ssq, g, b, scale, shift);
    int t = blockIdx.x * 256 + threadIdx.x;
    if (t >= 720000) return;
    float4 v = reinterpret_cast<const float4*>(x)[t];
    int d0 = (t * 4) % 96;
    ushort4 o;
    o.x = f2bf(fmaxf(v.x * scale[d0] + shift[d0], 0.f));
    o.y = f2bf(fmaxf(v.y * scale[d0 + 1] + shift[d0 + 1], 0.f));
    o.z = f2bf(fmaxf(v.z * scale[d0 + 2] + shift[d0 + 2], 0.f));
    o.w = f2bf(fmaxf(v.w * scale[d0 + 3] + shift[d0 + 3], 0.f));
    reinterpret_cast<ushort4*>(h)[t] = o;
    float4 z = {0.f, 0.f, 0.f, 0.f};
    reinterpret_cast<float4*>(x)[t] = z;
}

// SE MLP from raw segment sums: pooled = seg/cnt * scale2 + shift2
__global__ void k_se(const float* __restrict__ segsum, const float* __restrict__ cnt,
                     const float* __restrict__ ssum, const float* __restrict__ ssq,
                     const float* __restrict__ g, const float* __restrict__ b,
                     const float* __restrict__ fc1w, const float* __restrict__ fc1b,
                     const float* __restrict__ fc2w, const float* __restrict__ fc2b,
                     float* __restrict__ sew) {
    __shared__ float scale[96], shift[96];
    __shared__ float pooled[NB][96];
    __shared__ float hid[NB][HID];
    bn_coeffs(ssum, ssq, g, b, scale, shift);
    int t = threadIdx.x;
    for (int i = t; i < NB * 96; i += 256) {
        int bb = i / 96, d = i - bb * 96;
        pooled[bb][d] = segsum[i] / fmaxf(cnt[bb], 1.f) * scale[d] + shift[d];
    }
    __syncthreads();
    if (t < NB * HID) {
        int bb = t / HID, h = t - bb * HID;
        float s = fc1b[h];
        for (int d = 0; d < 96; ++d) s += pooled[bb][d] * fc1w[d * HID + h];
        hid[bb][h] = fmaxf(s, 0.f);
    }
    __syncthreads();
    for (int i = t; i < NB * 96; i += 256) {
        int bb = i / 96, d = i - bb * 96;
        float s = fc2b[d];
        for (int h = 0; h < HID; ++h) s += hid[bb][h] * fc2w[h * 96 + d];
        sew[i] = 1.f / (1.f + expf(-s));
    }
}

// final: relu( (y2*scale2+shift2) * sew[b] + feats )
__global__ void k_final(const float* __restrict__ out2, const float* __restrict__ feats,
                        const float* __restrict__ ssum, const float* __restrict__ ssq,
                        const float* __restrict__ g, const float* __restrict__ b,
                        const float* __restrict__ sew, const int* __restrict__ bids,
                        float* __restrict__ out) {
    __shared__ float scale[96], shift[96];
    bn_coeffs(ssum, ssq, g, b, scale, shift);
    int t = blockIdx.x * 256 + threadIdx.x;
    if (t >= 720000) return;
    int e0 = t * 4;
    int n = e0 / 96;
    int d0 = e0 - n * 96;
    int bb = bids[n];
    const float* w = sew + bb * 96;
    float4 v = reinterpret_cast<const float4*>(out2)[t];
    float4 f = reinterpret_cast<const float4*>(feats)[t];
    float4 o;
    o.x = fmaxf((v.x * scale[d0] + shift[d0]) * w[d0] + f.x, 0.f);
    o.y = fmaxf((v.y * scale[d0 + 1] + shift[d0 + 1]) * w[d0 + 1] + f.y, 0.f);
    o.z = fmaxf((v.z * scale[d0 + 2] + shift[d0 + 2]) * w[d0 + 2] + f.z, 0.f);
    o.w = fmaxf((v.w * scale[d0 + 3] + shift[d0 + 3]) * w[d0 + 3] + f.w, 0.f);
    reinterpret_cast<float4*>(out)[t] = o;
}

// ---------------- launch ----------------

extern "C" void kernel_launch(void* const* d_in, const int* in_sizes, int n_in,
                              void* d_out, int out_size, void* d_ws, size_t ws_size,
                              hipStream_t stream) {
    const float* feats = (const float*)d_in[0];
    const float* W1 = (const float*)d_in[1];
    const float* g1 = (const float*)d_in[2];
    const float* b1 = (const float*)d_in[3];
    const float* W2 = (const float*)d_in[4];
    const float* g2 = (const float*)d_in[5];
    const float* b2 = (const float*)d_in[6];
    const float* fc1w = (const float*)d_in[7];
    const float* fc1b = (const float*)d_in[8];
    const float* fc2w = (const float*)d_in[9];
    const float* fc2b = (const float*)d_in[10];
    const int* nbr = (const int*)d_in[11];
    const int* bids = (const int*)d_in[12];
    float* out = (float*)d_out;

    char* ws = (char*)d_ws;
    ushort* featsbf = (ushort*)(ws + 0);               // 5,760,000 B
    ushort* wt1 = (ushort*)(ws + 5760000);             // 1,492,992 B
    ushort* wt2 = (ushort*)(ws + 7252992);             // 1,492,992 B
    int* nbrT = (int*)(ws + 8745984);                  // 9,720,000 B
    float* outbuf = (float*)(ws + 18465984);           // 11,520,000 B
    ushort* h1bf = (ushort*)(ws + 29985984);           // 5,760,000 B
    float* small = (float*)(ws + 35745984);            // 16,384 B
    float* sum1 = small + 0;
    float* sq1 = small + 96;
    float* sum2 = small + 192;
    float* sq2 = small + 288;
    float* segsum = small + 768;   // [8][96]
    float* cntf = small + 1536;    // [8]
    float* sew = small + 1544;     // [8][96]

    const int gE = 2813;               // ceil(720000/256)
    const int gC = KSPLIT * GSPLIT;    // 2500 single-wave blocks

    hipMemsetAsync(small, 0, 16384, stream);
    k_prep<<<3444, 256, 0, stream>>>(feats, W1, W2, nbr, featsbf, outbuf, nbrT, wt1, wt2);

    k_conv<<<gC, 64, 0, stream>>>(featsbf, wt1, nbrT, outbuf);
    k_stats<false><<<256, 256, 0, stream>>>(outbuf, bids, sum1, sq1, segsum, cntf);
    k_apply1<<<gE, 256, 0, stream>>>(outbuf, sum1, sq1, g1, b1, h1bf);

    k_conv<<<gC, 64, 0, stream>>>(h1bf, wt2, nbrT, outbuf);
    k_stats<true><<<256, 256, 0, stream>>>(outbuf, bids, sum2, sq2, segsum, cntf);

    k_se<<<1, 256, 0, stream>>>(segsum, cntf, sum2, sq2, g2, b2, fc1w, fc1b, fc2w, fc2b, sew);
    k_final<<<gE, 256, 0, stream>>>(outbuf, feats, sum2, sq2, g2, b2, sew, bids, out);
}